// Round 9
// baseline (189.401 us; speedup 1.0000x reference)
//
#include <hip/hip_runtime.h>
#include <hip/hip_bf16.h>

typedef unsigned short u16;
typedef unsigned int u32;
typedef __attribute__((ext_vector_type(8))) short short8;
typedef __attribute__((ext_vector_type(4))) float f32x4;
typedef __attribute__((ext_vector_type(4))) u16 u16x4;

#define DEV __device__ __forceinline__

DEV u16 f2bf(float f) {
    union { float f; u32 u; } v; v.f = f;
    u32 r = v.u;
    u32 lsb = (r >> 16) & 1u;
    r += 0x7fffu + lsb;
    return (u16)(r >> 16);
}

DEV void gload_lds16(const u16* g, u16* l) {
    __builtin_amdgcn_global_load_lds(
        (const __attribute__((address_space(1))) u32*)(const void*)g,
        (__attribute__((address_space(3))) u32*)(void*)l,
        16, 0, 0);
}

// ---------------- merged prep: two weight transposes + RMSNorm, one launch ----------------
__global__ void prep(const float* __restrict__ x, const float* __restrict__ gamma,
                     const float* __restrict__ w_qkv, const float* __restrict__ w_out,
                     u16* __restrict__ xn, u16* __restrict__ wqkvT, u16* __restrict__ woutT) {
    __shared__ float tile[32][33];
    __shared__ float red[4];
    int id = blockIdx.x;
    int t = threadIdx.x;
    if (id < 8192) {
        const float* in; u16* out; int R, C, bx, by;
        if (id < 6144) { in = w_qkv; out = wqkvT; R = 2048; C = 3072; bx = id % 96; by = id / 96; }
        else { id -= 6144; in = w_out; out = woutT; R = 1024; C = 2048; bx = id % 64; by = id / 64; }
        int tx = t & 31, ty = t >> 5;
        int c0 = bx * 32, r0 = by * 32;
#pragma unroll
        for (int i = 0; i < 4; i++)
            tile[ty * 4 + i][tx] = in[(size_t)(r0 + ty * 4 + i) * C + c0 + tx];
        __syncthreads();
#pragma unroll
        for (int i = 0; i < 4; i++)
            out[(size_t)(c0 + ty * 4 + i) * R + r0 + tx] = f2bf(tile[tx][ty * 4 + i]);
    } else {
        int row = id - 8192;
        const float4* xr = (const float4*)(x + (size_t)row * 2048);
        float4 a = xr[t];
        float4 b = xr[256 + t];
        float ss = a.x * a.x + a.y * a.y + a.z * a.z + a.w * a.w +
                   b.x * b.x + b.y * b.y + b.z * b.z + b.w * b.w;
#pragma unroll
        for (int off = 32; off; off >>= 1) ss += __shfl_xor(ss, off);
        if ((t & 63) == 0) red[t >> 6] = ss;
        __syncthreads();
        float tot = red[0] + red[1] + red[2] + red[3];
        float n = sqrtf(tot);
        float inv = 45.254833995939045f / fmaxf(n, 1e-12f);
        const float4* gr = (const float4*)gamma;
        float4 g0 = gr[t], g1 = gr[256 + t];
        u16x4 o0 = { f2bf(a.x * inv * (g0.x + 1.f)), f2bf(a.y * inv * (g0.y + 1.f)),
                     f2bf(a.z * inv * (g0.z + 1.f)), f2bf(a.w * inv * (g0.w + 1.f)) };
        u16x4 o1 = { f2bf(b.x * inv * (g1.x + 1.f)), f2bf(b.y * inv * (g1.y + 1.f)),
                     f2bf(b.z * inv * (g1.z + 1.f)), f2bf(b.w * inv * (g1.w + 1.f)) };
        u16x4* xo = (u16x4*)(xn + (size_t)row * 2048);
        xo[t] = o0;
        xo[256 + t] = o1;
    }
}

// ---------------- 256x256 GEMM, register ping-pong schedule ----------------
// 8 waves (2M x 4N), wave tile 128x64, quadrants (qm,qn). LDS as gemm8f:
// As/Bs[2buf][2half][128 rows][64 k], chunk swizzle kc' = kc^(row&7) both sides.
// Per K-tile 4 phases, ONE barrier each; ds_reads for phase p+1 issued BEFORE
// phase p's MFMA; counted lgkmcnt overlaps LDS pipe with matrix pipe:
//  p1: rd B1 | stage BL(kt+1) | lgkm(4)  | MFMA(0,0)=a0*b0 | bar
//  p2: rd A1 | stage AH(kt+2) | lgkm(8)  | MFMA(0,1)=a0*b1 | bar
//  p3:                          lgkm(0)  | MFMA(1,0)=a1*b0 | bar
//  p4: stage AL+BH(kt+2) | vmcnt(6) | rd A0,B0(next buf) | MFMA(1,1)=a1*b1 | bar
// Slot-overwrite: every stage is >=1 barrier after its slot's reads completed
// (BL: read p1(kt-1)->staged p1(kt); AH: read p1 -> staged p2; AL: read p2,
//  done@p3-lgkm0+bar -> staged p4; BH: read p1 -> staged p4). vmcnt(6) at p4
// forces tile kt+1 landed before its reads issue in p4. sched_barrier(0)
// after each waitcnt stops MFMA hoisting (rule 18); all frag regs named (rule 20).
template <int EPI, int CCOL>
__global__ __launch_bounds__(512, 1) void gemmpp(
    const u16* __restrict__ A, const u16* __restrict__ BT,
    int M, int N, int K,
    float* __restrict__ Cout,
    u16* __restrict__ qb, u16* __restrict__ kb, u16* __restrict__ vT) {
    __shared__ __align__(16) u16 As[2][2][8192];
    __shared__ __align__(16) u16 Bs[2][2][8192];
    int t = threadIdx.x, lane = t & 63, wid = t >> 6;
    int g = lane >> 4, r = lane & 15;
    int wm = wid >> 2, wn = wid & 3;
    int rsw = r & 7;

    int id = blockIdx.x;
    int xcd = id & 7, slot = id >> 3;
    int by = (xcd >> 1) * 4 + slot / CCOL;
    int bx = (xcd & 1) * CCOL + slot % CCOL;
    int brow = by * 256, bcol = bx * 256;

    int gsl = (t & 7) ^ ((t >> 3) & 7);
    const u16* AgH = A + (size_t)(brow + (t >> 3)) * K + gsl * 8;
    const u16* BgH = BT + (size_t)(bcol + (t >> 3)) * K + gsl * 8;
    const size_t loK = (size_t)128 * K, r64K = (size_t)64 * K;
    int dstc = t * 8;

    f32x4 acc[2][4][2][2] = {};
    short8 a0[4][2], a1[4][2], b0[2][2], b1[2][2];
    int NT = K >> 6;

#define STG_AH(bf_, kt_) { gload_lds16(AgH + (kt_) * 64, &As[bf_][0][dstc]); \
                           gload_lds16(AgH + r64K + (kt_) * 64, &As[bf_][0][dstc + 4096]); }
#define STG_AL(bf_, kt_) { gload_lds16(AgH + loK + (kt_) * 64, &As[bf_][1][dstc]); \
                           gload_lds16(AgH + loK + r64K + (kt_) * 64, &As[bf_][1][dstc + 4096]); }
#define STG_BH(bf_, kt_) { gload_lds16(BgH + (kt_) * 64, &Bs[bf_][0][dstc]); \
                           gload_lds16(BgH + r64K + (kt_) * 64, &Bs[bf_][0][dstc + 4096]); }
#define STG_BL(bf_, kt_) { gload_lds16(BgH + loK + (kt_) * 64, &Bs[bf_][1][dstc]); \
                           gload_lds16(BgH + loK + r64K + (kt_) * 64, &Bs[bf_][1][dstc + 4096]); }
#define RD_A(dst_, bb_, hh_) { \
    _Pragma("unroll") for (int mf = 0; mf < 4; mf++) \
    _Pragma("unroll") for (int ks = 0; ks < 2; ks++) \
        dst_[mf][ks] = *(const short8*)&As[bb_][hh_][(wm * 64 + mf * 16 + r) * 64 + (((ks << 2) + g) ^ rsw) * 8]; }
#define RD_B(dst_, bb_, hh_) { \
    _Pragma("unroll") for (int nf = 0; nf < 2; nf++) \
    _Pragma("unroll") for (int ks = 0; ks < 2; ks++) \
        dst_[nf][ks] = *(const short8*)&Bs[bb_][hh_][(wn * 32 + nf * 16 + r) * 64 + (((ks << 2) + g) ^ rsw) * 8]; }
#define MFMA_Q(qm_, qn_, aa_, bb_) { \
    __builtin_amdgcn_s_setprio(1); \
    _Pragma("unroll") for (int ks = 0; ks < 2; ks++) \
    _Pragma("unroll") for (int mf = 0; mf < 4; mf++) \
    _Pragma("unroll") for (int nf = 0; nf < 2; nf++) \
        acc[qm_][mf][qn_][nf] = __builtin_amdgcn_mfma_f32_16x16x32_bf16( \
            aa_[mf][ks], bb_[nf][ks], acc[qm_][mf][qn_][nf], 0, 0, 0); \
    __builtin_amdgcn_s_setprio(0); }
#define SCHEDB() __builtin_amdgcn_sched_barrier(0)
#define BAR() __builtin_amdgcn_s_barrier()

    // prologue: T0 all halves + T1 {AH, AL, BH}; T0 proven landed; initial reads
    STG_AH(0, 0); STG_AL(0, 0); STG_BH(0, 0); STG_BL(0, 0);
    if (NT > 1) { STG_AH(1, 1); STG_AL(1, 1); STG_BH(1, 1); }
    asm volatile("s_waitcnt vmcnt(6)" ::: "memory");
    SCHEDB();
    BAR();
    RD_A(a0, 0, 0);
    RD_B(b0, 0, 0);

    for (int kt = 0; kt < NT; ++kt) {
        int buf = kt & 1, ob = buf ^ 1;
        bool s1 = kt + 1 < NT, s2 = kt + 2 < NT;

        // ---- p1: MFMA(0,0); read B1; stage BL(kt+1) ----
        RD_B(b1, buf, 1);
        if (s1) STG_BL(ob, kt + 1);
        asm volatile("s_waitcnt lgkmcnt(4)" ::: "memory");
        SCHEDB();
        MFMA_Q(0, 0, a0, b0);
        BAR();

        // ---- p2: MFMA(0,1); read A1; stage AH(kt+2) ----
        RD_A(a1, buf, 1);
        if (s2) STG_AH(buf, kt + 2);
        asm volatile("s_waitcnt lgkmcnt(8)" ::: "memory");
        SCHEDB();
        MFMA_Q(0, 1, a0, b1);
        BAR();

        // ---- p3: MFMA(1,0) ----
        asm volatile("s_waitcnt lgkmcnt(0)" ::: "memory");
        SCHEDB();
        MFMA_Q(1, 0, a1, b0);
        BAR();

        // ---- p4: stage AL+BH(kt+2); vmcnt; read next A0,B0; MFMA(1,1) ----
        if (s2) { STG_AL(buf, kt + 2); STG_BH(buf, kt + 2); }
        if (s2)      { asm volatile("s_waitcnt vmcnt(6)" ::: "memory"); }
        else if (s1) { asm volatile("s_waitcnt vmcnt(0)" ::: "memory"); }
        SCHEDB();
        if (s1) { RD_A(a0, ob, 0); RD_B(b0, ob, 0); }
        MFMA_Q(1, 1, a1, b1);
        BAR();
    }
#undef STG_AH
#undef STG_AL
#undef STG_BH
#undef STG_BL
#undef RD_A
#undef RD_B
#undef MFMA_Q
#undef SCHEDB
#undef BAR

    if (EPI == 0) {
#pragma unroll
        for (int qm = 0; qm < 2; qm++)
#pragma unroll
            for (int mf = 0; mf < 4; mf++)
#pragma unroll
                for (int qn = 0; qn < 2; qn++)
#pragma unroll
                    for (int nf = 0; nf < 2; nf++) {
                        int cb = bcol + qn * 128 + wn * 32 + nf * 16 + r;
                        int which = cb >> 10;
                        int hd = cb & 1023;
                        int hh = hd >> 6, d = hd & 63;
#pragma unroll
                        for (int j = 0; j < 4; j++) {
                            int rr = brow + qm * 128 + wm * 64 + mf * 16 + 4 * g + j;
                            int b = rr >> 11, nn = rr & 2047;
                            float v = acc[qm][mf][qn][nf][j];
                            size_t bh = (size_t)(b * 16 + hh);
                            if (which == 0)      qb[(bh * 2048 + nn) * 64 + d] = f2bf(v * 0.125f);
                            else if (which == 1) kb[(bh * 2048 + nn) * 64 + d] = f2bf(v);
                            else                 vT[(bh * 64 + d) * 2048 + nn] = f2bf(v);
                        }
                    }
    } else {
#pragma unroll
        for (int qm = 0; qm < 2; qm++)
#pragma unroll
            for (int mf = 0; mf < 4; mf++)
#pragma unroll
                for (int qn = 0; qn < 2; qn++)
#pragma unroll
                    for (int nf = 0; nf < 2; nf++) {
                        int cb = bcol + qn * 128 + wn * 32 + nf * 16 + r;
#pragma unroll
                        for (int j = 0; j < 4; j++) {
                            int rr = brow + qm * 128 + wm * 64 + mf * 16 + 4 * g + j;
                            Cout[(size_t)rr * N + cb] = acc[qm][mf][qn][nf][j];
                        }
                    }
    }
}

// ---------------- flash attention v3: block-shared LDS K/V, double-buffered ----------------
__global__ __launch_bounds__(256, 3) void flash_attn(
    const u16* __restrict__ q, const u16* __restrict__ kk, const u16* __restrict__ vT,
    const int* __restrict__ mods, u16* __restrict__ attn_out) {
    __shared__ __align__(16) u16 Ks[2][4096];
    __shared__ __align__(16) u16 Vs[2][4096];
    __shared__ __align__(16) u16 Plds[4][16][72];
    int t = threadIdx.x, lane = t & 63, wave = t >> 6;
    int g = lane >> 4, r = lane & 15;
    int h = blockIdx.x, b = blockIdx.y;
    int qs = (31 - blockIdx.z) * 64;          // longest q-blocks dispatched first
    int bh = b * 16 + h;
    int qbase = qs + wave * 16;

    int off0 = mods[b * 6 + 1], end0 = off0 + mods[b * 6 + 2];
    int off1 = mods[b * 6 + 4], end1 = off1 + mods[b * 6 + 5];

    const u16* Qp = q + ((size_t)bh * 2048 + qbase) * 64;
    short8 qf0 = *(const short8*)(Qp + (size_t)r * 64 + 8 * g);
    short8 qf1 = *(const short8*)(Qp + (size_t)r * 64 + 32 + 8 * g);

    int iq = qbase + r;
    int lim0 = (iq >= off0) ? end0 : 0;
    int lim1 = (iq >= off1) ? end1 : 0;
    int rowlim = max(iq + 1, max(lim0, lim1));

    int jlb = qs + 64;
    if (qs + 63 >= off0) jlb = max(jlb, end0);
    if (qs + 63 >= off1) jlb = max(jlb, end1);

    const u16* Kp = kk + (size_t)bh * 2048 * 64;
    const u16* Vp = vT + (size_t)bh * 64 * 2048;
    u16* Pw = &Plds[wave][0][0];

    f32x4 ot[4] = {};
    float psA = 0.f, psB = 0.f;
    int sw = r & 7;

    auto stage64 = [&](const u16* gbase, int gstride, u16* lds) {
#pragma unroll
        for (int i = 0; i < 2; i++) {
            int c = i * 256 + t;
            int row = c >> 3;
            int gsl = (c & 7) ^ (row & 7);
            gload_lds16(gbase + (size_t)row * gstride + 8 * gsl,
                        lds + (size_t)(c & ~63) * 8);
        }
    };

    stage64(Kp, 64, Ks[0]);
    stage64(Vp, 2048, Vs[0]);
    int buf = 0;

    for (int jb = 0; jb < jlb; jb += 64) {
        if (jb + 64 < jlb) {
            stage64(Kp + (size_t)(jb + 64) * 64, 64, Ks[buf ^ 1]);
            stage64(Vp + (jb + 64), 2048, Vs[buf ^ 1]);
            asm volatile("s_waitcnt vmcnt(4)" ::: "memory");
        } else {
            asm volatile("s_waitcnt vmcnt(0)" ::: "memory");
        }
        __builtin_amdgcn_s_barrier();
        const u16* Kt = Ks[buf];
        const u16* Vt = Vs[buf];

        f32x4 st[4];
#pragma unroll
        for (int tt = 0; tt < 4; tt++) {
            int row = 16 * tt + r;
            short8 kf0 = *(const short8*)&Kt[(size_t)(row * 8 + (g ^ sw)) * 8];
            short8 kf1 = *(const short8*)&Kt[(size_t)(row * 8 + ((4 + g) ^ sw)) * 8];
            f32x4 z = {};
            z = __builtin_amdgcn_mfma_f32_16x16x32_bf16(kf0, qf0, z, 0, 0, 0);
            z = __builtin_amdgcn_mfma_f32_16x16x32_bf16(kf1, qf1, z, 0, 0, 0);
            st[tt] = z;
        }
#pragma unroll
        for (int tt = 0; tt < 4; tt++) {
            int kvb = jb + 16 * tt + 4 * g;
            float p0, p1, p2, p3;
#pragma unroll
            for (int j = 0; j < 4; j++) {
                float x = st[tt][j];
                float x2 = x * x;
                float inner = __builtin_fmaf(x2, 2.1333333e-8f, -1.3333333e-4f);
                float poly = __builtin_fmaf(x2, inner, 1.0f);
                float pv = __expf(x * poly);
                pv = (kvb + j < rowlim) ? pv : 0.f;
                if (j == 0) p0 = pv; else if (j == 1) p1 = pv;
                else if (j == 2) p2 = pv; else p3 = pv;
            }
            psA += p0 + p1;
            psB += p2 + p3;
            u32 pk0, pk1;
            asm("v_cvt_pk_bf16_f32 %0, %1, %2" : "=v"(pk0) : "v"(p0), "v"(p1));
            asm("v_cvt_pk_bf16_f32 %0, %1, %2" : "=v"(pk1) : "v"(p2), "v"(p3));
            *(u32*)&Pw[r * 72 + 16 * tt + 4 * g] = pk0;
            *(u32*)&Pw[r * 72 + 16 * tt + 4 * g + 2] = pk1;
        }
        short8 pf0 = *(const short8*)&Pw[r * 72 + 8 * g];
        short8 pf1 = *(const short8*)&Pw[r * 72 + 32 + 8 * g];
#pragma unroll
        for (int dt = 0; dt < 4; dt++) {
            int row = 16 * dt + r;
            short8 vf0 = *(const short8*)&Vt[(size_t)(row * 8 + (g ^ sw)) * 8];
            short8 vf1 = *(const short8*)&Vt[(size_t)(row * 8 + ((4 + g) ^ sw)) * 8];
            ot[dt] = __builtin_amdgcn_mfma_f32_16x16x32_bf16(vf0, pf0, ot[dt], 0, 0, 0);
            ot[dt] = __builtin_amdgcn_mfma_f32_16x16x32_bf16(vf1, pf1, ot[dt], 0, 0, 0);
        }
        asm volatile("s_waitcnt lgkmcnt(0)" ::: "memory");
        __builtin_amdgcn_s_barrier();
        buf ^= 1;
    }

    float lrow = psA + psB;
    lrow += __shfl_xor(lrow, 16);
    lrow += __shfl_xor(lrow, 32);
    float inv = 1.f / lrow;
    u16* Op = attn_out + ((size_t)(b * 2048 + qbase + r)) * 1024 + h * 64;
#pragma unroll
    for (int dt = 0; dt < 4; dt++) {
        u16x4 o = { f2bf(ot[dt][0] * inv), f2bf(ot[dt][1] * inv),
                    f2bf(ot[dt][2] * inv), f2bf(ot[dt][3] * inv) };
        *(u16x4*)(Op + dt * 16 + 4 * g) = o;
    }
}

extern "C" void kernel_launch(void* const* d_in, const int* in_sizes, int n_in,
                              void* d_out, int out_size, void* d_ws, size_t ws_size,
                              hipStream_t stream) {
    const float* x = (const float*)d_in[0];
    const float* gamma = (const float*)d_in[1];
    const float* w_qkv = (const float*)d_in[2];
    const float* w_out = (const float*)d_in[3];
    const int* mods = (const int*)d_in[4];
    float* out = (float*)d_out;

    u16* ws = (u16*)d_ws;
    u16* xn    = ws;                 // 4096*2048
    u16* wqkvT = ws + 8388608;       // 3072*2048
    u16* woutT = ws + 14680064;      // 2048*1024
    u16* qb    = ws + 16777216;      // 2*16*2048*64
    u16* kb    = ws + 20971520;
    u16* vT    = ws + 25165824;
    u16* ao    = ws + 29360128;      // 4096*1024

    prep<<<dim3(12288), dim3(256), 0, stream>>>(x, gamma, w_qkv, w_out, xn, wqkvT, woutT);
    gemmpp<0, 6><<<dim3(192), dim3(512), 0, stream>>>(xn, wqkvT, 4096, 3072, 2048,
                                                      nullptr, qb, kb, vT);
    flash_attn<<<dim3(16, 2, 32), dim3(256), 0, stream>>>(qb, kb, vT, mods, ao);
    gemmpp<1, 4><<<dim3(128), dim3(512), 0, stream>>>(ao, woutT, 4096, 2048, 1024,
                                                      out, nullptr, nullptr, nullptr);
}

// Round 10
// 164.099 us; speedup vs baseline: 1.1542x; 1.1542x over previous
//
#include <hip/hip_runtime.h>
#include <hip/hip_bf16.h>

typedef unsigned short u16;
typedef unsigned int u32;
typedef __attribute__((ext_vector_type(8))) short short8;
typedef __attribute__((ext_vector_type(4))) float f32x4;
typedef __attribute__((ext_vector_type(4))) u16 u16x4;

#define DEV __device__ __forceinline__

DEV u16 f2bf(float f) {
    union { float f; u32 u; } v; v.f = f;
    u32 r = v.u;
    u32 lsb = (r >> 16) & 1u;
    r += 0x7fffu + lsb;
    return (u16)(r >> 16);
}

DEV void gload_lds16(const u16* g, u16* l) {
    __builtin_amdgcn_global_load_lds(
        (const __attribute__((address_space(1))) u32*)(const void*)g,
        (__attribute__((address_space(3))) u32*)(void*)l,
        16, 0, 0);
}

// ---------------- merged prep: two weight transposes + RMSNorm, one launch ----------------
__global__ void prep(const float* __restrict__ x, const float* __restrict__ gamma,
                     const float* __restrict__ w_qkv, const float* __restrict__ w_out,
                     u16* __restrict__ xn, u16* __restrict__ wqkvT, u16* __restrict__ woutT) {
    __shared__ float tile[32][33];
    __shared__ float red[4];
    int id = blockIdx.x;
    int t = threadIdx.x;
    if (id < 8192) {
        const float* in; u16* out; int R, C, bx, by;
        if (id < 6144) { in = w_qkv; out = wqkvT; R = 2048; C = 3072; bx = id % 96; by = id / 96; }
        else { id -= 6144; in = w_out; out = woutT; R = 1024; C = 2048; bx = id % 64; by = id / 64; }
        int tx = t & 31, ty = t >> 5;
        int c0 = bx * 32, r0 = by * 32;
#pragma unroll
        for (int i = 0; i < 4; i++)
            tile[ty * 4 + i][tx] = in[(size_t)(r0 + ty * 4 + i) * C + c0 + tx];
        __syncthreads();
#pragma unroll
        for (int i = 0; i < 4; i++)
            out[(size_t)(c0 + ty * 4 + i) * R + r0 + tx] = f2bf(tile[tx][ty * 4 + i]);
    } else {
        int row = id - 8192;
        const float4* xr = (const float4*)(x + (size_t)row * 2048);
        float4 a = xr[t];
        float4 b = xr[256 + t];
        float ss = a.x * a.x + a.y * a.y + a.z * a.z + a.w * a.w +
                   b.x * b.x + b.y * b.y + b.z * b.z + b.w * b.w;
#pragma unroll
        for (int off = 32; off; off >>= 1) ss += __shfl_xor(ss, off);
        if ((t & 63) == 0) red[t >> 6] = ss;
        __syncthreads();
        float tot = red[0] + red[1] + red[2] + red[3];
        float n = sqrtf(tot);
        float inv = 45.254833995939045f / fmaxf(n, 1e-12f);
        const float4* gr = (const float4*)gamma;
        float4 g0 = gr[t], g1 = gr[256 + t];
        u16x4 o0 = { f2bf(a.x * inv * (g0.x + 1.f)), f2bf(a.y * inv * (g0.y + 1.f)),
                     f2bf(a.z * inv * (g0.z + 1.f)), f2bf(a.w * inv * (g0.w + 1.f)) };
        u16x4 o1 = { f2bf(b.x * inv * (g1.x + 1.f)), f2bf(b.y * inv * (g1.y + 1.f)),
                     f2bf(b.z * inv * (g1.z + 1.f)), f2bf(b.w * inv * (g1.w + 1.f)) };
        u16x4* xo = (u16x4*)(xn + (size_t)row * 2048);
        xo[t] = o0;
        xo[256 + t] = o1;
    }
}

// ---------------- 256xBN GEMM with column-half B slots (full-GPU grids) ----------------
// 8 waves (2M x 4N), BM=256, BK=64. A slots [2buf][2 row-half][128][64];
// B slots [2buf][2 col-half][HN=BN/2][64]. Each wave's BN/4 cols lie in ONE
// col-half (bhalf = wn>>1). 16B-chunk swizzle kc' = kc^(row&7), both sides.
// K-tile = 4 phases: p1{rd B(all)+A0 | stg B1(kt+1)->ob | lgkm0 | MFMA q0/G0}
// p2{stg B0(kt+1)->ob, A0(kt+2)->buf | MFMA q0/G1} p3{rd A1 | lgkm0 | MFMA q1/G0}
// p4{stg A1(kt+2)->buf | MFMA q1/G1 | vmcnt(4)}; 1 barrier per phase.
// Hazards: every stage is >=1 barrier after its slot's reads (B read p1 of prev
// buf cycle; A0 read p1; A1 read p3). vmcnt(4) = newest 4 loads (A kt+2) may
// remain; forces B(kt+1)+A(kt+1) landed before kt+1 p1 reads.
template <int EPI, int BN, int CCOL>
__global__ __launch_bounds__(512, 1) void gemmcf(
    const u16* __restrict__ A, const u16* __restrict__ BT,
    int M, int N, int K,
    float* __restrict__ Cout,
    u16* __restrict__ qb, u16* __restrict__ kb, u16* __restrict__ vT) {
    constexpr int HN = BN / 2;          // cols per half (96 or 64)
    constexpr int NF2 = BN / 64;        // n-frags per wave (3 or 2)
    constexpr int NG0 = (NF2 + 1) / 2;  // frags in MFMA group 0
    constexpr bool B2 = (HN * 8) > 512; // B half needs a 2nd chunk (t<256)
    __shared__ __align__(16) u16 As[2][2][8192];
    __shared__ __align__(16) u16 Bs[2][2][HN * 64];
    int t = threadIdx.x, lane = t & 63, wid = t >> 6;
    int g = lane >> 4, r = lane & 15;
    int wm = wid >> 2, wn = wid & 3;
    int bhalf = wn >> 1;
    int cb0w = (wn & 1) * (BN / 4);
    int rsw = r & 7;

    int id = blockIdx.x;
    int xcd = id & 7, slot = id >> 3;
    int by = (xcd >> 1) * 4 + slot / CCOL;
    int bx = (xcd & 1) * CCOL + slot % CCOL;
    int brow = by * 256, bcol = bx * BN;

    int gsl = (t & 7) ^ ((t >> 3) & 7);
    const u16* Ag = A + (size_t)(brow + (t >> 3)) * K + gsl * 8;
    const u16* Bg = BT + (size_t)(bcol + (t >> 3)) * K + gsl * 8;
    int dstc = t * 8;

    f32x4 acc[2][4][NF2] = {};
    short8 areg[4][2], breg[NF2][2];
    int NT = K >> 6;

#define STG_A(bf_, kt_, h_) { \
        gload_lds16(Ag + (size_t)((h_) * 128) * K + (kt_) * 64, &As[bf_][h_][dstc]); \
        gload_lds16(Ag + (size_t)((h_) * 128 + 64) * K + (kt_) * 64, &As[bf_][h_][4096 + dstc]); }
#define STG_B(bf_, kt_, h_) { \
        gload_lds16(Bg + (size_t)((h_) * HN) * K + (kt_) * 64, &Bs[bf_][h_][dstc]); \
        if constexpr (B2) { if (t < 256) \
            gload_lds16(Bg + (size_t)((h_) * HN + 64) * K + (kt_) * 64, &Bs[bf_][h_][4096 + dstc]); } }
#define RD_A(qm_) { \
    _Pragma("unroll") for (int mf = 0; mf < 4; mf++) \
    _Pragma("unroll") for (int ks = 0; ks < 2; ks++) \
        areg[mf][ks] = *(const short8*)&As[buf][qm_][(wm * 64 + mf * 16 + r) * 64 + (((ks << 2) + g) ^ rsw) * 8]; }
#define RD_B() { \
    _Pragma("unroll") for (int nf = 0; nf < NF2; nf++) \
    _Pragma("unroll") for (int ks = 0; ks < 2; ks++) \
        breg[nf][ks] = *(const short8*)&Bs[buf][bhalf][(cb0w + nf * 16 + r) * 64 + (((ks << 2) + g) ^ rsw) * 8]; }
#define MFMA_G(qm_, nf0_, nf1_) { \
    __builtin_amdgcn_s_setprio(1); \
    _Pragma("unroll") for (int ks = 0; ks < 2; ks++) \
    _Pragma("unroll") for (int mf = 0; mf < 4; mf++) \
    _Pragma("unroll") for (int nf = nf0_; nf < nf1_; nf++) \
        acc[qm_][mf][nf] = __builtin_amdgcn_mfma_f32_16x16x32_bf16( \
            areg[mf][ks], breg[nf][ks], acc[qm_][mf][nf], 0, 0, 0); \
    __builtin_amdgcn_s_setprio(0); }
#define SCHEDB() __builtin_amdgcn_sched_barrier(0)
#define BAR() __builtin_amdgcn_s_barrier()

    // prologue: tile0 all slots, then A(tile1); vmcnt(4) leaves A(1) in flight
    STG_A(0, 0, 0); STG_A(0, 0, 1); STG_B(0, 0, 0); STG_B(0, 0, 1);
    if (NT > 1) { STG_A(1, 1, 0); STG_A(1, 1, 1); }
    if (NT > 1) { asm volatile("s_waitcnt vmcnt(4)" ::: "memory"); }
    else        { asm volatile("s_waitcnt vmcnt(0)" ::: "memory"); }
    SCHEDB();
    BAR();

    for (int kt = 0; kt < NT; ++kt) {
        int buf = kt & 1, ob = buf ^ 1;
        bool s1 = kt + 1 < NT, s2 = kt + 2 < NT;

        // ---- p1: read B(all)+A0; stage B-half1(kt+1)->ob ----
        RD_B(); RD_A(0);
        if (s1) STG_B(ob, kt + 1, 1);
        asm volatile("s_waitcnt lgkmcnt(0)" ::: "memory");
        SCHEDB();
        MFMA_G(0, 0, NG0);
        BAR();

        // ---- p2: stage B-half0(kt+1)->ob, A0(kt+2)->buf ----
        if (s1) STG_B(ob, kt + 1, 0);
        if (s2) STG_A(buf, kt + 2, 0);
        MFMA_G(0, NG0, NF2);
        BAR();

        // ---- p3: read A1 ----
        RD_A(1);
        asm volatile("s_waitcnt lgkmcnt(0)" ::: "memory");
        SCHEDB();
        MFMA_G(1, 0, NG0);
        BAR();

        // ---- p4: stage A1(kt+2)->buf; boundary vmcnt ----
        if (s2) STG_A(buf, kt + 2, 1);
        MFMA_G(1, NG0, NF2);
        if (s2)      { asm volatile("s_waitcnt vmcnt(4)" ::: "memory"); }
        else if (s1) { asm volatile("s_waitcnt vmcnt(0)" ::: "memory"); }
        SCHEDB();
        BAR();
    }
#undef STG_A
#undef STG_B
#undef RD_A
#undef RD_B
#undef MFMA_G
#undef SCHEDB
#undef BAR

    if (EPI == 0) {
#pragma unroll
        for (int qm = 0; qm < 2; qm++)
#pragma unroll
            for (int mf = 0; mf < 4; mf++)
#pragma unroll
                for (int nf = 0; nf < NF2; nf++) {
                    int cb = bcol + bhalf * HN + cb0w + nf * 16 + r;
                    int which = cb >> 10;
                    int hd = cb & 1023;
                    int hh = hd >> 6, d = hd & 63;
#pragma unroll
                    for (int j = 0; j < 4; j++) {
                        int rr = brow + qm * 128 + wm * 64 + mf * 16 + 4 * g + j;
                        int b = rr >> 11, nn = rr & 2047;
                        float v = acc[qm][mf][nf][j];
                        size_t bh = (size_t)(b * 16 + hh);
                        if (which == 0)      qb[(bh * 2048 + nn) * 64 + d] = f2bf(v * 0.125f);
                        else if (which == 1) kb[(bh * 2048 + nn) * 64 + d] = f2bf(v);
                        else                 vT[(bh * 64 + d) * 2048 + nn] = f2bf(v);
                    }
                }
    } else {
#pragma unroll
        for (int qm = 0; qm < 2; qm++)
#pragma unroll
            for (int mf = 0; mf < 4; mf++)
#pragma unroll
                for (int nf = 0; nf < NF2; nf++) {
                    int cb = bcol + bhalf * HN + cb0w + nf * 16 + r;
#pragma unroll
                    for (int j = 0; j < 4; j++) {
                        int rr = brow + qm * 128 + wm * 64 + mf * 16 + 4 * g + j;
                        Cout[(size_t)rr * N + cb] = acc[qm][mf][nf][j];
                    }
                }
    }
}

// ---------------- flash attention v3: block-shared LDS K/V, double-buffered ----------------
__global__ __launch_bounds__(256, 3) void flash_attn(
    const u16* __restrict__ q, const u16* __restrict__ kk, const u16* __restrict__ vT,
    const int* __restrict__ mods, u16* __restrict__ attn_out) {
    __shared__ __align__(16) u16 Ks[2][4096];
    __shared__ __align__(16) u16 Vs[2][4096];
    __shared__ __align__(16) u16 Plds[4][16][72];
    int t = threadIdx.x, lane = t & 63, wave = t >> 6;
    int g = lane >> 4, r = lane & 15;
    int h = blockIdx.x, b = blockIdx.y;
    int qs = (31 - blockIdx.z) * 64;          // longest q-blocks dispatched first
    int bh = b * 16 + h;
    int qbase = qs + wave * 16;

    int off0 = mods[b * 6 + 1], end0 = off0 + mods[b * 6 + 2];
    int off1 = mods[b * 6 + 4], end1 = off1 + mods[b * 6 + 5];

    const u16* Qp = q + ((size_t)bh * 2048 + qbase) * 64;
    short8 qf0 = *(const short8*)(Qp + (size_t)r * 64 + 8 * g);
    short8 qf1 = *(const short8*)(Qp + (size_t)r * 64 + 32 + 8 * g);

    int iq = qbase + r;
    int lim0 = (iq >= off0) ? end0 : 0;
    int lim1 = (iq >= off1) ? end1 : 0;
    int rowlim = max(iq + 1, max(lim0, lim1));

    int jlb = qs + 64;
    if (qs + 63 >= off0) jlb = max(jlb, end0);
    if (qs + 63 >= off1) jlb = max(jlb, end1);

    const u16* Kp = kk + (size_t)bh * 2048 * 64;
    const u16* Vp = vT + (size_t)bh * 64 * 2048;
    u16* Pw = &Plds[wave][0][0];

    f32x4 ot[4] = {};
    float psA = 0.f, psB = 0.f;
    int sw = r & 7;

    auto stage64 = [&](const u16* gbase, int gstride, u16* lds) {
#pragma unroll
        for (int i = 0; i < 2; i++) {
            int c = i * 256 + t;
            int row = c >> 3;
            int gsl = (c & 7) ^ (row & 7);
            gload_lds16(gbase + (size_t)row * gstride + 8 * gsl,
                        lds + (size_t)(c & ~63) * 8);
        }
    };

    stage64(Kp, 64, Ks[0]);
    stage64(Vp, 2048, Vs[0]);
    int buf = 0;

    for (int jb = 0; jb < jlb; jb += 64) {
        if (jb + 64 < jlb) {
            stage64(Kp + (size_t)(jb + 64) * 64, 64, Ks[buf ^ 1]);
            stage64(Vp + (jb + 64), 2048, Vs[buf ^ 1]);
            asm volatile("s_waitcnt vmcnt(4)" ::: "memory");
        } else {
            asm volatile("s_waitcnt vmcnt(0)" ::: "memory");
        }
        __builtin_amdgcn_s_barrier();
        const u16* Kt = Ks[buf];
        const u16* Vt = Vs[buf];

        f32x4 st[4];
#pragma unroll
        for (int tt = 0; tt < 4; tt++) {
            int row = 16 * tt + r;
            short8 kf0 = *(const short8*)&Kt[(size_t)(row * 8 + (g ^ sw)) * 8];
            short8 kf1 = *(const short8*)&Kt[(size_t)(row * 8 + ((4 + g) ^ sw)) * 8];
            f32x4 z = {};
            z = __builtin_amdgcn_mfma_f32_16x16x32_bf16(kf0, qf0, z, 0, 0, 0);
            z = __builtin_amdgcn_mfma_f32_16x16x32_bf16(kf1, qf1, z, 0, 0, 0);
            st[tt] = z;
        }
#pragma unroll
        for (int tt = 0; tt < 4; tt++) {
            int kvb = jb + 16 * tt + 4 * g;
            float p0, p1, p2, p3;
#pragma unroll
            for (int j = 0; j < 4; j++) {
                float x = st[tt][j];
                float x2 = x * x;
                float inner = __builtin_fmaf(x2, 2.1333333e-8f, -1.3333333e-4f);
                float poly = __builtin_fmaf(x2, inner, 1.0f);
                float pv = __expf(x * poly);
                pv = (kvb + j < rowlim) ? pv : 0.f;
                if (j == 0) p0 = pv; else if (j == 1) p1 = pv;
                else if (j == 2) p2 = pv; else p3 = pv;
            }
            psA += p0 + p1;
            psB += p2 + p3;
            u32 pk0, pk1;
            asm("v_cvt_pk_bf16_f32 %0, %1, %2" : "=v"(pk0) : "v"(p0), "v"(p1));
            asm("v_cvt_pk_bf16_f32 %0, %1, %2" : "=v"(pk1) : "v"(p2), "v"(p3));
            *(u32*)&Pw[r * 72 + 16 * tt + 4 * g] = pk0;
            *(u32*)&Pw[r * 72 + 16 * tt + 4 * g + 2] = pk1;
        }
        short8 pf0 = *(const short8*)&Pw[r * 72 + 8 * g];
        short8 pf1 = *(const short8*)&Pw[r * 72 + 32 + 8 * g];
#pragma unroll
        for (int dt = 0; dt < 4; dt++) {
            int row = 16 * dt + r;
            short8 vf0 = *(const short8*)&Vt[(size_t)(row * 8 + (g ^ sw)) * 8];
            short8 vf1 = *(const short8*)&Vt[(size_t)(row * 8 + ((4 + g) ^ sw)) * 8];
            ot[dt] = __builtin_amdgcn_mfma_f32_16x16x32_bf16(vf0, pf0, ot[dt], 0, 0, 0);
            ot[dt] = __builtin_amdgcn_mfma_f32_16x16x32_bf16(vf1, pf1, ot[dt], 0, 0, 0);
        }
        asm volatile("s_waitcnt lgkmcnt(0)" ::: "memory");
        __builtin_amdgcn_s_barrier();
        buf ^= 1;
    }

    float lrow = psA + psB;
    lrow += __shfl_xor(lrow, 16);
    lrow += __shfl_xor(lrow, 32);
    float inv = 1.f / lrow;
    u16* Op = attn_out + ((size_t)(b * 2048 + qbase + r)) * 1024 + h * 64;
#pragma unroll
    for (int dt = 0; dt < 4; dt++) {
        u16x4 o = { f2bf(ot[dt][0] * inv), f2bf(ot[dt][1] * inv),
                    f2bf(ot[dt][2] * inv), f2bf(ot[dt][3] * inv) };
        *(u16x4*)(Op + dt * 16 + 4 * g) = o;
    }
}

extern "C" void kernel_launch(void* const* d_in, const int* in_sizes, int n_in,
                              void* d_out, int out_size, void* d_ws, size_t ws_size,
                              hipStream_t stream) {
    const float* x = (const float*)d_in[0];
    const float* gamma = (const float*)d_in[1];
    const float* w_qkv = (const float*)d_in[2];
    const float* w_out = (const float*)d_in[3];
    const int* mods = (const int*)d_in[4];
    float* out = (float*)d_out;

    u16* ws = (u16*)d_ws;
    u16* xn    = ws;                 // 4096*2048
    u16* wqkvT = ws + 8388608;       // 3072*2048
    u16* woutT = ws + 14680064;      // 2048*1024
    u16* qb    = ws + 16777216;      // 2*16*2048*64
    u16* kb    = ws + 20971520;
    u16* vT    = ws + 25165824;
    u16* ao    = ws + 29360128;      // 4096*1024

    prep<<<dim3(12288), dim3(256), 0, stream>>>(x, gamma, w_qkv, w_out, xn, wqkvT, woutT);
    gemmcf<0, 192, 8><<<dim3(256), dim3(512), 0, stream>>>(xn, wqkvT, 4096, 3072, 2048,
                                                           nullptr, qb, kb, vT);
    flash_attn<<<dim3(16, 2, 32), dim3(256), 0, stream>>>(qb, kb, vT, mods, ao);
    gemmcf<1, 128, 8><<<dim3(256), dim3(512), 0, stream>>>(ao, woutT, 4096, 2048, 1024,
                                                           out, nullptr, nullptr, nullptr);
}